// Round 1
// baseline (1146.305 us; speedup 1.0000x reference)
//
#include <hip/hip_runtime.h>

#define BB 256
#define NPER 512
#define FF 256
#define DD 32
#define EE 524288
#define NN (BB*NPER)          // 131072
#define NSTEPS 4
#define SPLIT 8

// ---------------- kernels ----------------

// scatter: s[dst] += relu([xs,q][src] @ W_in + b_in)  (h recomputed on the fly)
__global__ void k_scatter(const int* __restrict__ src, const int* __restrict__ dst,
                          const float* __restrict__ xs, const float* __restrict__ q,
                          const float* __restrict__ Win, const float* __restrict__ bin,
                          float* __restrict__ s, float* __restrict__ degf) {
    int t = blockIdx.x * blockDim.x + threadIdx.x;   // E*32 threads
    int e = t >> 5, d = t & 31;
    int sv = src[e], dv = dst[e];
    float hv = xs[sv] * Win[d] + q[sv] * Win[DD + d] + bin[d];
    hv = fmaxf(hv, 0.f);
    atomicAdd(&s[dv * DD + d], hv);
    if (d == 0) atomicAdd(&degf[dv], 1.0f);
}

// per node: agg = s_row@W_msg + deg*b_msg ; h2 = relu(h+agg); pred = h2@W_out + b_out
__global__ void k_node(const float* __restrict__ xs, const float* __restrict__ q,
                       const float* __restrict__ Win, const float* __restrict__ bin,
                       const float* __restrict__ s, const float* __restrict__ degf,
                       const float* __restrict__ Wmsg, const float* __restrict__ bmsg,
                       const float* __restrict__ Wout, const float* __restrict__ bout,
                       float* __restrict__ pred, float* __restrict__ out_preds, int step) {
    __shared__ float Wm[DD * DD];
    __shared__ float sl[8 * DD];
    int tid = threadIdx.x;                  // 256 = 8 nodes x 32 channels
    int i = blockIdx.x * 8 + (tid >> 5);
    int d = tid & 31;
    for (int k = tid; k < DD * DD; k += 256) Wm[k] = Wmsg[k];
    sl[tid] = s[i * DD + d];
    __syncthreads();
    float hval = fmaxf(xs[i] * Win[d] + q[i] * Win[DD + d] + bin[d], 0.f);
    float agg = degf[i] * bmsg[d];
    const float* srow = &sl[(tid >> 5) * DD];
    #pragma unroll
    for (int k = 0; k < DD; ++k) agg += srow[k] * Wm[k * DD + d];
    float h2 = fmaxf(hval + agg, 0.f);
    float v = h2 * Wout[d];
    for (int o = 16; o > 0; o >>= 1) v += __shfl_down(v, o, 32);
    if (d == 0) {
        float pr = v + bout[0];
        pred[i] = pr;
        out_preds[i * NSTEPS + step] = pr;
    }
}

// per graph (one block of 512): labels, normalized direction, zero df, init alphaMin
__global__ void k_graph(const float* __restrict__ xs, const float* __restrict__ xsol,
                        const float* __restrict__ pred,
                        float* __restrict__ out_labels, float* __restrict__ dd,
                        float* __restrict__ df, unsigned int* __restrict__ alphaMin,
                        float tau, int step) {
    __shared__ float red[NPER];
    int b = blockIdx.x;
    int t = threadIdx.x;                 // 512
    int i = b * NPER + t;
    float x = xs[i];
    float r = xsol[i] - x;
    float p = pred[i];
    red[t] = fabsf(r);
    __syncthreads();
    for (int o = 256; o > 0; o >>= 1) { if (t < o) red[t] += red[t + o]; __syncthreads(); }
    float Sr = red[0] + 1e-12f;
    __syncthreads();
    red[t] = fabsf(p);
    __syncthreads();
    for (int o = 256; o > 0; o >>= 1) { if (t < o) red[t] += red[t + o]; __syncthreads(); }
    float Sp = red[0] + 1e-12f;
    out_labels[i * NSTEPS + step] = r / Sr;
    dd[i] = p / Sp + 3.0f * tau / (x + tau);
    if (t < FF) df[b * FF + t] = 0.f;
    if (t == 0) alphaMin[b] = 0x7f800000u;   // +inf bits (ratios are >= 0)
}

// df[b,f] = sum_n P[b,n,f] * dd[b,n]  (split over n, atomic combine)
__global__ void k_df(const float* __restrict__ P, const float* __restrict__ dd,
                     float* __restrict__ df) {
    __shared__ float dl[NPER / SPLIT];   // 64
    int b  = blockIdx.x / SPLIT;
    int sp = blockIdx.x % SPLIT;
    int f  = threadIdx.x;                // 256
    int n0 = sp * (NPER / SPLIT);
    if (f < NPER / SPLIT) dl[f] = dd[b * NPER + n0 + f];
    __syncthreads();
    const float* Pb = P + ((size_t)b * NPER + n0) * FF + f;
    float acc = 0.f;
    #pragma unroll 4
    for (int n = 0; n < NPER / SPLIT; ++n) acc += Pb[(size_t)n * FF] * dl[n];
    atomicAdd(&df[b * FF + f], acc);
}

// pproj[b,n] = sum_f P[b,n,f]*df[b,f]; line-search ratio; per-graph atomic min
__global__ void k_pproj(const float* __restrict__ P, const float* __restrict__ df,
                        const float* __restrict__ xs,
                        float* __restrict__ pproj, unsigned int* __restrict__ alphaMin) {
    __shared__ float mred[4];
    int t = threadIdx.x;                 // 256 = 4 waves, one node each
    int w = t >> 6;
    int lane = t & 63;
    int n = blockIdx.x * 4 + w;          // 4 aligned nodes -> all in same graph
    int b = n >> 9;
    const float* Pr  = P + (size_t)n * FF;
    const float* dfb = df + (size_t)b * FF;
    float acc = 0.f;
    #pragma unroll
    for (int c = 0; c < FF / 64; ++c) acc += Pr[c * 64 + lane] * dfb[c * 64 + lane];
    for (int o = 32; o > 0; o >>= 1) acc += __shfl_down(acc, o, 64);
    if (lane == 0) {
        pproj[n] = acc;
        float x = xs[n];
        float ratio = (acc < 0.f) ? (x / fmaxf(-acc, 1e-12f)) : 5.0f;
        mred[w] = ratio;
    }
    __syncthreads();
    if (t == 0) {
        float m = fminf(fminf(mred[0], mred[1]), fminf(mred[2], mred[3]));
        atomicMin(&alphaMin[b], __float_as_uint(m));
    }
}

__global__ void k_update(const unsigned int* __restrict__ alphaMin,
                         const float* __restrict__ pproj, float* __restrict__ xs) {
    int i = blockIdx.x * blockDim.x + threadIdx.x;
    int b = i >> 9;
    float a = __uint_as_float(alphaMin[b]);
    a = fminf(fmaxf(a, 0.f), 5.0f) * 0.995f;
    xs[i] += a * pproj[i];
}

// ---------------- launch ----------------

extern "C" void kernel_launch(void* const* d_in, const int* in_sizes, int n_in,
                              void* d_out, int out_size, void* d_ws, size_t ws_size,
                              hipStream_t stream) {
    const float* x_start = (const float*)d_in[0];
    const float* x_sol   = (const float*)d_in[1];
    const float* q       = (const float*)d_in[2];
    const float* P       = (const float*)d_in[3];
    const float* Win     = (const float*)d_in[4];
    const float* bin     = (const float*)d_in[5];
    const float* Wmsg    = (const float*)d_in[6];
    const float* bmsg    = (const float*)d_in[7];
    const float* Wout    = (const float*)d_in[8];
    const float* bout    = (const float*)d_in[9];
    const int*   esrc    = (const int*)d_in[10];
    const int*   edst    = (const int*)d_in[11];
    // d_in[12] vals_batch unused: batch(i) == i >> 9 (equal-sized contiguous graphs)

    float* out_preds  = (float*)d_out;                // [N, 4] row-major
    float* out_labels = (float*)d_out + (size_t)NN * NSTEPS;

    float* w = (float*)d_ws;
    float* xs    = w; w += NN;
    float* s     = w; w += (size_t)NN * DD;
    float* degf  = w; w += NN;                        // s+degf contiguous for one memset
    float* pred  = w; w += NN;
    float* ddv   = w; w += NN;
    float* pproj = w; w += NN;
    float* df    = w; w += BB * FF;
    unsigned int* alphaMin = (unsigned int*)w; w += BB;

    hipMemcpyAsync(xs, x_start, NN * sizeof(float), hipMemcpyDeviceToDevice, stream);

    float tau = 0.1f;
    for (int step = 0; step < NSTEPS; ++step) {
        hipMemsetAsync(s, 0, (size_t)(NN * DD + NN) * sizeof(float), stream); // s + degf
        k_scatter<<<EE * DD / 256, 256, 0, stream>>>(esrc, edst, xs, q, Win, bin, s, degf);
        k_node<<<NN / 8, 256, 0, stream>>>(xs, q, Win, bin, s, degf, Wmsg, bmsg, Wout, bout,
                                           pred, out_preds, step);
        k_graph<<<BB, NPER, 0, stream>>>(xs, x_sol, pred, out_labels, ddv, df, alphaMin,
                                         tau, step);
        k_df<<<BB * SPLIT, 256, 0, stream>>>(P, ddv, df);
        k_pproj<<<NN / 4, 256, 0, stream>>>(P, df, xs, pproj, alphaMin);
        k_update<<<NN / 256, 256, 0, stream>>>(alphaMin, pproj, xs);
        tau = fmaxf(tau * 0.5f, 1e-5f);
    }
}